// Round 7
// baseline (327.696 us; speedup 1.0000x reference)
//
#include <hip/hip_runtime.h>
#include <cmath>

#define WS  11
#define NX  160
#define NXY (NX*NX)
#define NB  2
#define TH  16
#define TW  32
#define MH  26              // mid rows = TH + 10
#define MST 36              // mid row stride
#define DCHUNK 20
#define PLANE_I 8192000     // NB*NX*NX*NX

struct GaussW { float g[WS]; };

// k_wh: per (b,d) slice, 16x32 tile. Phase 1: W-blur straight from global
// (5 float4 loads per array per thread -> 20-col register window), 5 fields on
// the fly, write mid[5][26][36] to LDS. Barrier. Phase 2: H-blur (4 rows x
// 4 cols x 1 field per thread, b128 reads), store planar A[f].
// launch_bounds(256,8): VGPR cap 64 (used 44 at cap 128); LDS 8x18.9KB=151.5KB.
__global__ __launch_bounds__(256, 8) void k_wh(const float* __restrict__ x,
                                               const float* __restrict__ y,
                                               float* __restrict__ A,
                                               GaussW gw) {
    __shared__ float mid[5][MH][MST];     // 18.72 KB

    const int tid = threadIdx.x;
    const int b  = blockIdx.z / NX;
    const int d  = blockIdx.z % NX;
    const int h0 = blockIdx.y * TH;
    const int w0 = blockIdx.x * TW;
    const int slice = (b * NX + d) * NXY;

    // ---- Phase 1: W-blur, 208 threads = 26 rows x 8 col-quads ----
    if (tid < 208) {
        const int wr = tid >> 3;          // 0..25
        const int wq = tid & 7;           // 0..7
        const int gh = h0 - 5 + wr;
        const bool rowok = (unsigned)gh < (unsigned)NX;
        const int c0 = w0 + 4 * wq - 8;   // first loaded col (float4-aligned)
        const int rbase = slice + gh * NX;

        float wx[20], wy[20];
        #pragma unroll
        for (int i = 0; i < 5; ++i) {
            const int ci = c0 + 4 * i;
            float4 xv = {0,0,0,0}, yv = {0,0,0,0};
            if (rowok) {
                if (ci >= 0 && ci + 3 < NX) {
                    xv = *(const float4*)(x + rbase + ci);
                    yv = *(const float4*)(y + rbase + ci);
                } else {
                    float ex[4] = {0,0,0,0}, ey[4] = {0,0,0,0};
                    #pragma unroll
                    for (int e = 0; e < 4; ++e)
                        if ((unsigned)(ci + e) < (unsigned)NX) {
                            ex[e] = x[rbase + ci + e];
                            ey[e] = y[rbase + ci + e];
                        }
                    xv = make_float4(ex[0], ex[1], ex[2], ex[3]);
                    yv = make_float4(ey[0], ey[1], ey[2], ey[3]);
                }
            }
            wx[4*i] = xv.x; wx[4*i+1] = xv.y; wx[4*i+2] = xv.z; wx[4*i+3] = xv.w;
            wy[4*i] = yv.x; wy[4*i+1] = yv.y; wy[4*i+2] = yv.z; wy[4*i+3] = yv.w;
        }
        float a0[4] = {0,0,0,0}, a1[4] = {0,0,0,0}, a2[4] = {0,0,0,0},
              a3[4] = {0,0,0,0}, a4[4] = {0,0,0,0};
        #pragma unroll
        for (int k = 0; k < WS; ++k) {
            const float gk = gw.g[k];
            #pragma unroll
            for (int jj = 0; jj < 4; ++jj) {
                const float xv = wx[3 + jj + k];
                const float yv = wy[3 + jj + k];
                const float t0 = gk * xv, t1 = gk * yv;
                a0[jj] += t0;       a1[jj] += t1;
                a2[jj] += t0 * xv;  a3[jj] += t1 * yv;  a4[jj] += t0 * yv;
            }
        }
        *(float4*)&mid[0][wr][4*wq] = make_float4(a0[0], a0[1], a0[2], a0[3]);
        *(float4*)&mid[1][wr][4*wq] = make_float4(a1[0], a1[1], a1[2], a1[3]);
        *(float4*)&mid[2][wr][4*wq] = make_float4(a2[0], a2[1], a2[2], a2[3]);
        *(float4*)&mid[3][wr][4*wq] = make_float4(a3[0], a3[1], a3[2], a3[3]);
        *(float4*)&mid[4][wr][4*wq] = make_float4(a4[0], a4[1], a4[2], a4[3]);
    }
    __syncthreads();

    // ---- Phase 2: H-blur, 160 threads = 5 fields x 4 row-groups x 8 col-quads ----
    if (tid < 160) {
        const int hf  = tid >> 5;
        const int hr0 = ((tid >> 3) & 3) << 2;
        const int hq4 = (tid & 7) << 2;
        float4 o0 = {0,0,0,0}, o1 = {0,0,0,0}, o2 = {0,0,0,0}, o3 = {0,0,0,0};
        #pragma unroll
        for (int k2 = 0; k2 < 14; ++k2) {
            const float4 v = *(const float4*)&mid[hf][hr0 + k2][hq4];
            if (k2 <= 10) { const float g = gw.g[k2];
                o0.x += g*v.x; o0.y += g*v.y; o0.z += g*v.z; o0.w += g*v.w; }
            if (k2 >= 1 && k2 <= 11) { const float g = gw.g[k2-1];
                o1.x += g*v.x; o1.y += g*v.y; o1.z += g*v.z; o1.w += g*v.w; }
            if (k2 >= 2 && k2 <= 12) { const float g = gw.g[k2-2];
                o2.x += g*v.x; o2.y += g*v.y; o2.z += g*v.z; o2.w += g*v.w; }
            if (k2 >= 3) { const float g = gw.g[k2-3];
                o3.x += g*v.x; o3.y += g*v.y; o3.z += g*v.z; o3.w += g*v.w; }
        }
        const int obase = hf * PLANE_I + slice + (h0 + hr0) * NX + w0 + hq4;
        *(float4*)(A + obase)          = o0;
        *(float4*)(A + obase + NX)     = o1;
        *(float4*)(A + obase + 2*NX)   = o2;
        *(float4*)(A + obase + 3*NX)   = o3;
    }
}

// k_d: D-blur + SSIM + reduce. Full unroll -> static ring indices (the
// win[f][i]=win[f][i+1] shifts rename away instead of ~50 v_mov/iter).
// DCHUNK=20 -> 1600 blocks = 25 waves/CU.
__global__ __launch_bounds__(256, 4) void k_d(const float* __restrict__ A,
                                              float* __restrict__ partial,
                                              GaussW gw) {
    const int tid = threadIdx.x;
    const long long gidx = (long long)blockIdx.x * 256 + tid;
    const int NCOL = NB * NX * NX;
    const int chunk = (int)(gidx / NCOL);
    const int col   = (int)(gidx % NCOL);
    const int b  = col / (NX * NX);
    const int hw = col % (NX * NX);
    const int base = b * (NX * NXY) + hw;
    const int d0 = chunk * DCHUNK;

    float win[5][WS];
    #pragma unroll
    for (int i = 0; i < WS; ++i) {
        const int di = d0 - 5 + i;
        const bool ok = (di >= 0 && di < NX);
        const int o = base + (ok ? di : 0) * NXY;
        #pragma unroll
        for (int f = 0; f < 5; ++f)
            win[f][i] = ok ? A[f * PLANE_I + o] : 0.f;
    }

    float acc = 0.f;
    #pragma unroll
    for (int dd = 0; dd < DCHUNK; ++dd) {
        float m[5];
        #pragma unroll
        for (int f = 0; f < 5; ++f) {
            float s = 0.f;
            #pragma unroll
            for (int i = 0; i < WS; ++i) s += gw.g[i] * win[f][i];
            m[f] = s;
        }
        const float mux = m[0], muy = m[1];
        const float mux2 = mux * mux, muy2 = muy * muy, muxy = mux * muy;
        const float sxx = m[2] - mux2, syy = m[3] - muy2, sxy = m[4] - muxy;
        const float num = (2.f * muxy + 1.0e-4f) * (2.f * sxy + 9.0e-4f);
        const float den = (mux2 + muy2 + 1.0e-4f) * (sxx + syy + 9.0e-4f);
        acc += num / den;

        const int dn = d0 + dd + 6;
        const bool ok = (dn < NX);
        const int o = base + (ok ? dn : 0) * NXY;
        #pragma unroll
        for (int f = 0; f < 5; ++f) {
            #pragma unroll
            for (int i = 0; i < WS - 1; ++i) win[f][i] = win[f][i + 1];
            win[f][WS - 1] = ok ? A[f * PLANE_I + o] : 0.f;
        }
    }

    for (int off = 32; off > 0; off >>= 1) acc += __shfl_down(acc, off, 64);
    __shared__ float wsum[4];
    if ((tid & 63) == 0) wsum[tid >> 6] = acc;
    __syncthreads();
    if (tid == 0) partial[blockIdx.x] = wsum[0] + wsum[1] + wsum[2] + wsum[3];
}

__global__ __launch_bounds__(256) void k_red(const float* __restrict__ partial,
                                             int n, float* __restrict__ out) {
    double s = 0.0;
    for (int i = threadIdx.x; i < n; i += 256) s += (double)partial[i];
    __shared__ double sd[256];
    sd[threadIdx.x] = s;
    __syncthreads();
    for (int st = 128; st > 0; st >>= 1) {
        if (threadIdx.x < st) sd[threadIdx.x] += sd[threadIdx.x + st];
        __syncthreads();
    }
    if (threadIdx.x == 0)
        out[0] = (float)(sd[0] / (double)((long long)NB * NX * NXY));
}

extern "C" void kernel_launch(void* const* d_in, const int* in_sizes, int n_in,
                              void* d_out, int out_size, void* d_ws, size_t ws_size,
                              hipStream_t stream) {
    const float* x = (const float*)d_in[0];
    const float* y = (const float*)d_in[1];
    float* A = (float*)d_ws;
    float* partial = (float*)((char*)d_ws + (size_t)5 * PLANE_I * sizeof(float));

    GaussW gw;
    {
        float tmp[WS]; float s = 0.f;
        for (int i = 0; i < WS; ++i) {
            const double e = exp(-(double)((i - 5) * (i - 5)) / 4.5);
            tmp[i] = (float)e; s += tmp[i];
        }
        for (int i = 0; i < WS; ++i) gw.g[i] = tmp[i] / s;
    }

    dim3 g1(NX / TW, NX / TH, NB * NX);   // (5,10,320) = 16000 blocks
    k_wh<<<g1, 256, 0, stream>>>(x, y, A, gw);

    const int nblk2 = (NB * NX * NX * (NX / DCHUNK)) / 256;  // 1600
    k_d<<<nblk2, 256, 0, stream>>>(A, partial, gw);

    k_red<<<1, 256, 0, stream>>>(partial, nblk2, (float*)d_out);
}

// Round 8
// 139.714 us; speedup vs baseline: 2.3455x; 2.3455x over previous
//
#include <hip/hip_runtime.h>
#include <cmath>

#define WS  11
#define NX  160
#define NXY (NX*NX)
#define NB  2
#define TH  16
#define TW  32
#define MH  26              // mid rows = TH + 10
#define MST 36              // mid row stride
#define DCHUNK 40
#define PLANE_I 8192000     // NB*NX*NX*NX

struct GaussW { float g[WS]; };

// k_wh: per (b,d) slice, 16x32 tile. Phase 1: W-blur straight from global
// (5 float4 loads per array per thread -> 20-col register window), 5 fields on
// the fly, write mid[5][26][36] to LDS. Barrier. Phase 2: H-blur (4 rows x
// 4 cols x 1 field per thread, b128 reads), store planar A[f].
// Occupancy tracks the waves-per-EU hint (r5:,2->22%, r6:,4->49%, r7:,8->87%).
// (256,6): VGPR budget ~85 >= 44 used -> no squeeze/spill (r7's ,8 squeezed to
// 32 VGPR and spilled 475MB), target 24 waves/CU.
__global__ __launch_bounds__(256, 6) void k_wh(const float* __restrict__ x,
                                               const float* __restrict__ y,
                                               float* __restrict__ A,
                                               GaussW gw) {
    __shared__ float mid[5][MH][MST];     // 18.72 KB

    const int tid = threadIdx.x;
    const int b  = blockIdx.z / NX;
    const int d  = blockIdx.z % NX;
    const int h0 = blockIdx.y * TH;
    const int w0 = blockIdx.x * TW;
    const int slice = (b * NX + d) * NXY;

    // ---- Phase 1: W-blur, 208 threads = 26 rows x 8 col-quads ----
    if (tid < 208) {
        const int wr = tid >> 3;          // 0..25
        const int wq = tid & 7;           // 0..7
        const int gh = h0 - 5 + wr;
        const bool rowok = (unsigned)gh < (unsigned)NX;
        const int c0 = w0 + 4 * wq - 8;   // first loaded col (float4-aligned)
        const int rbase = slice + gh * NX;

        float wx[20], wy[20];
        #pragma unroll
        for (int i = 0; i < 5; ++i) {
            const int ci = c0 + 4 * i;
            float4 xv = {0,0,0,0}, yv = {0,0,0,0};
            if (rowok) {
                if (ci >= 0 && ci + 3 < NX) {
                    xv = *(const float4*)(x + rbase + ci);
                    yv = *(const float4*)(y + rbase + ci);
                } else {
                    float ex[4] = {0,0,0,0}, ey[4] = {0,0,0,0};
                    #pragma unroll
                    for (int e = 0; e < 4; ++e)
                        if ((unsigned)(ci + e) < (unsigned)NX) {
                            ex[e] = x[rbase + ci + e];
                            ey[e] = y[rbase + ci + e];
                        }
                    xv = make_float4(ex[0], ex[1], ex[2], ex[3]);
                    yv = make_float4(ey[0], ey[1], ey[2], ey[3]);
                }
            }
            wx[4*i] = xv.x; wx[4*i+1] = xv.y; wx[4*i+2] = xv.z; wx[4*i+3] = xv.w;
            wy[4*i] = yv.x; wy[4*i+1] = yv.y; wy[4*i+2] = yv.z; wy[4*i+3] = yv.w;
        }
        float a0[4] = {0,0,0,0}, a1[4] = {0,0,0,0}, a2[4] = {0,0,0,0},
              a3[4] = {0,0,0,0}, a4[4] = {0,0,0,0};
        #pragma unroll
        for (int k = 0; k < WS; ++k) {
            const float gk = gw.g[k];
            #pragma unroll
            for (int jj = 0; jj < 4; ++jj) {
                const float xv = wx[3 + jj + k];
                const float yv = wy[3 + jj + k];
                const float t0 = gk * xv, t1 = gk * yv;
                a0[jj] += t0;       a1[jj] += t1;
                a2[jj] += t0 * xv;  a3[jj] += t1 * yv;  a4[jj] += t0 * yv;
            }
        }
        *(float4*)&mid[0][wr][4*wq] = make_float4(a0[0], a0[1], a0[2], a0[3]);
        *(float4*)&mid[1][wr][4*wq] = make_float4(a1[0], a1[1], a1[2], a1[3]);
        *(float4*)&mid[2][wr][4*wq] = make_float4(a2[0], a2[1], a2[2], a2[3]);
        *(float4*)&mid[3][wr][4*wq] = make_float4(a3[0], a3[1], a3[2], a3[3]);
        *(float4*)&mid[4][wr][4*wq] = make_float4(a4[0], a4[1], a4[2], a4[3]);
    }
    __syncthreads();

    // ---- Phase 2: H-blur, 160 threads = 5 fields x 4 row-groups x 8 col-quads ----
    if (tid < 160) {
        const int hf  = tid >> 5;
        const int hr0 = ((tid >> 3) & 3) << 2;
        const int hq4 = (tid & 7) << 2;
        float4 o0 = {0,0,0,0}, o1 = {0,0,0,0}, o2 = {0,0,0,0}, o3 = {0,0,0,0};
        #pragma unroll
        for (int k2 = 0; k2 < 14; ++k2) {
            const float4 v = *(const float4*)&mid[hf][hr0 + k2][hq4];
            if (k2 <= 10) { const float g = gw.g[k2];
                o0.x += g*v.x; o0.y += g*v.y; o0.z += g*v.z; o0.w += g*v.w; }
            if (k2 >= 1 && k2 <= 11) { const float g = gw.g[k2-1];
                o1.x += g*v.x; o1.y += g*v.y; o1.z += g*v.z; o1.w += g*v.w; }
            if (k2 >= 2 && k2 <= 12) { const float g = gw.g[k2-2];
                o2.x += g*v.x; o2.y += g*v.y; o2.z += g*v.z; o2.w += g*v.w; }
            if (k2 >= 3) { const float g = gw.g[k2-3];
                o3.x += g*v.x; o3.y += g*v.y; o3.z += g*v.z; o3.w += g*v.w; }
        }
        const int obase = hf * PLANE_I + slice + (h0 + hr0) * NX + w0 + hq4;
        *(float4*)(A + obase)          = o0;
        *(float4*)(A + obase + NX)     = o1;
        *(float4*)(A + obase + 2*NX)   = o2;
        *(float4*)(A + obase + 3*NX)   = o3;
    }
}

// k_d: D-blur with register sliding window + SSIM + block reduce.
// (proven config: DCHUNK=40, 800 blocks, no outer unroll — r7's DCHUNK=20 +
// full unroll regressed k_d+red 23->38us)
__global__ __launch_bounds__(256) void k_d(const float* __restrict__ A,
                                           float* __restrict__ partial,
                                           GaussW gw) {
    const int tid = threadIdx.x;
    const long long gidx = (long long)blockIdx.x * 256 + tid;
    const int NCOL = NB * NX * NX;
    const int chunk = (int)(gidx / NCOL);
    const int col   = (int)(gidx % NCOL);
    const int b  = col / (NX * NX);
    const int hw = col % (NX * NX);
    const int base = b * (NX * NXY) + hw;
    const int d0 = chunk * DCHUNK;

    float win[5][WS];
    #pragma unroll
    for (int i = 0; i < WS; ++i) {
        const int di = d0 - 5 + i;
        const bool ok = (di >= 0 && di < NX);
        const int o = base + (ok ? di : 0) * NXY;
        #pragma unroll
        for (int f = 0; f < 5; ++f)
            win[f][i] = ok ? A[f * PLANE_I + o] : 0.f;
    }

    float acc = 0.f;
    for (int dd = 0; dd < DCHUNK; ++dd) {
        float m[5];
        #pragma unroll
        for (int f = 0; f < 5; ++f) {
            float s = 0.f;
            #pragma unroll
            for (int i = 0; i < WS; ++i) s += gw.g[i] * win[f][i];
            m[f] = s;
        }
        const float mux = m[0], muy = m[1];
        const float mux2 = mux * mux, muy2 = muy * muy, muxy = mux * muy;
        const float sxx = m[2] - mux2, syy = m[3] - muy2, sxy = m[4] - muxy;
        const float num = (2.f * muxy + 1.0e-4f) * (2.f * sxy + 9.0e-4f);
        const float den = (mux2 + muy2 + 1.0e-4f) * (sxx + syy + 9.0e-4f);
        acc += num / den;

        const int dn = d0 + dd + 6;
        const bool ok = (dn < NX);
        const int o = base + (ok ? dn : 0) * NXY;
        #pragma unroll
        for (int f = 0; f < 5; ++f) {
            #pragma unroll
            for (int i = 0; i < WS - 1; ++i) win[f][i] = win[f][i + 1];
            win[f][WS - 1] = ok ? A[f * PLANE_I + o] : 0.f;
        }
    }

    for (int off = 32; off > 0; off >>= 1) acc += __shfl_down(acc, off, 64);
    __shared__ float wsum[4];
    if ((tid & 63) == 0) wsum[tid >> 6] = acc;
    __syncthreads();
    if (tid == 0) partial[blockIdx.x] = wsum[0] + wsum[1] + wsum[2] + wsum[3];
}

__global__ __launch_bounds__(256) void k_red(const float* __restrict__ partial,
                                             int n, float* __restrict__ out) {
    double s = 0.0;
    for (int i = threadIdx.x; i < n; i += 256) s += (double)partial[i];
    __shared__ double sd[256];
    sd[threadIdx.x] = s;
    __syncthreads();
    for (int st = 128; st > 0; st >>= 1) {
        if (threadIdx.x < st) sd[threadIdx.x] += sd[threadIdx.x + st];
        __syncthreads();
    }
    if (threadIdx.x == 0)
        out[0] = (float)(sd[0] / (double)((long long)NB * NX * NXY));
}

extern "C" void kernel_launch(void* const* d_in, const int* in_sizes, int n_in,
                              void* d_out, int out_size, void* d_ws, size_t ws_size,
                              hipStream_t stream) {
    const float* x = (const float*)d_in[0];
    const float* y = (const float*)d_in[1];
    float* A = (float*)d_ws;
    float* partial = (float*)((char*)d_ws + (size_t)5 * PLANE_I * sizeof(float));

    GaussW gw;
    {
        float tmp[WS]; float s = 0.f;
        for (int i = 0; i < WS; ++i) {
            const double e = exp(-(double)((i - 5) * (i - 5)) / 4.5);
            tmp[i] = (float)e; s += tmp[i];
        }
        for (int i = 0; i < WS; ++i) gw.g[i] = tmp[i] / s;
    }

    dim3 g1(NX / TW, NX / TH, NB * NX);   // (5,10,320) = 16000 blocks
    k_wh<<<g1, 256, 0, stream>>>(x, y, A, gw);

    const int nblk2 = (NB * NX * NX * (NX / DCHUNK)) / 256;  // 800
    k_d<<<nblk2, 256, 0, stream>>>(A, partial, gw);

    k_red<<<1, 256, 0, stream>>>(partial, nblk2, (float*)d_out);
}

// Round 9
// 116.357 us; speedup vs baseline: 2.8163x; 1.2007x over previous
//
#include <hip/hip_runtime.h>
#include <cmath>

#define WS  11
#define NX  160
#define NXY (NX*NX)
#define NB  2
#define TH  16
#define TW  32
#define MH  26              // mid rows = TH + 10
#define MST 36              // mid row stride
#define DCHUNK 40
#define PLANE_I 8192000     // NB*NX*NX*NX

struct GaussW { float g[WS]; };

// k_wh: per (b,d) slice, 16x32 tile. Phase 1: W-blur straight from global
// (5 float4 loads per array per thread -> 20-col register window), 5 fields on
// the fly, write mid[5][26][36] to LDS. Barrier. Phase 2: H-blur (4 rows x
// 4 cols x 1 field per thread, b128 reads), store planar A[f].
// Empirical hint table: (,4)->VGPR44 occ49% 93us | (,5)->THIS | (,6)->VGPR40
// spills 110MB 126us | (,8)->VGPR32 spills 475MB 290us. Budget ~ floor(256/hint)
// granule 8 -> hint5 gives 48 >= 44 needed: highest spill-free occupancy point.
__global__ __launch_bounds__(256, 5) void k_wh(const float* __restrict__ x,
                                               const float* __restrict__ y,
                                               float* __restrict__ A,
                                               GaussW gw) {
    __shared__ float mid[5][MH][MST];     // 18.72 KB

    const int tid = threadIdx.x;
    const int b  = blockIdx.z / NX;
    const int d  = blockIdx.z % NX;
    const int h0 = blockIdx.y * TH;
    const int w0 = blockIdx.x * TW;
    const int slice = (b * NX + d) * NXY;

    // ---- Phase 1: W-blur, 208 threads = 26 rows x 8 col-quads ----
    if (tid < 208) {
        const int wr = tid >> 3;          // 0..25
        const int wq = tid & 7;           // 0..7
        const int gh = h0 - 5 + wr;
        const bool rowok = (unsigned)gh < (unsigned)NX;
        const int c0 = w0 + 4 * wq - 8;   // first loaded col (float4-aligned)
        const int rbase = slice + gh * NX;

        float wx[20], wy[20];
        #pragma unroll
        for (int i = 0; i < 5; ++i) {
            const int ci = c0 + 4 * i;
            float4 xv = {0,0,0,0}, yv = {0,0,0,0};
            if (rowok) {
                if (ci >= 0 && ci + 3 < NX) {
                    xv = *(const float4*)(x + rbase + ci);
                    yv = *(const float4*)(y + rbase + ci);
                } else {
                    float ex[4] = {0,0,0,0}, ey[4] = {0,0,0,0};
                    #pragma unroll
                    for (int e = 0; e < 4; ++e)
                        if ((unsigned)(ci + e) < (unsigned)NX) {
                            ex[e] = x[rbase + ci + e];
                            ey[e] = y[rbase + ci + e];
                        }
                    xv = make_float4(ex[0], ex[1], ex[2], ex[3]);
                    yv = make_float4(ey[0], ey[1], ey[2], ey[3]);
                }
            }
            wx[4*i] = xv.x; wx[4*i+1] = xv.y; wx[4*i+2] = xv.z; wx[4*i+3] = xv.w;
            wy[4*i] = yv.x; wy[4*i+1] = yv.y; wy[4*i+2] = yv.z; wy[4*i+3] = yv.w;
        }
        float a0[4] = {0,0,0,0}, a1[4] = {0,0,0,0}, a2[4] = {0,0,0,0},
              a3[4] = {0,0,0,0}, a4[4] = {0,0,0,0};
        #pragma unroll
        for (int k = 0; k < WS; ++k) {
            const float gk = gw.g[k];
            #pragma unroll
            for (int jj = 0; jj < 4; ++jj) {
                const float xv = wx[3 + jj + k];
                const float yv = wy[3 + jj + k];
                const float t0 = gk * xv, t1 = gk * yv;
                a0[jj] += t0;       a1[jj] += t1;
                a2[jj] += t0 * xv;  a3[jj] += t1 * yv;  a4[jj] += t0 * yv;
            }
        }
        *(float4*)&mid[0][wr][4*wq] = make_float4(a0[0], a0[1], a0[2], a0[3]);
        *(float4*)&mid[1][wr][4*wq] = make_float4(a1[0], a1[1], a1[2], a1[3]);
        *(float4*)&mid[2][wr][4*wq] = make_float4(a2[0], a2[1], a2[2], a2[3]);
        *(float4*)&mid[3][wr][4*wq] = make_float4(a3[0], a3[1], a3[2], a3[3]);
        *(float4*)&mid[4][wr][4*wq] = make_float4(a4[0], a4[1], a4[2], a4[3]);
    }
    __syncthreads();

    // ---- Phase 2: H-blur, 160 threads = 5 fields x 4 row-groups x 8 col-quads ----
    if (tid < 160) {
        const int hf  = tid >> 5;
        const int hr0 = ((tid >> 3) & 3) << 2;
        const int hq4 = (tid & 7) << 2;
        float4 o0 = {0,0,0,0}, o1 = {0,0,0,0}, o2 = {0,0,0,0}, o3 = {0,0,0,0};
        #pragma unroll
        for (int k2 = 0; k2 < 14; ++k2) {
            const float4 v = *(const float4*)&mid[hf][hr0 + k2][hq4];
            if (k2 <= 10) { const float g = gw.g[k2];
                o0.x += g*v.x; o0.y += g*v.y; o0.z += g*v.z; o0.w += g*v.w; }
            if (k2 >= 1 && k2 <= 11) { const float g = gw.g[k2-1];
                o1.x += g*v.x; o1.y += g*v.y; o1.z += g*v.z; o1.w += g*v.w; }
            if (k2 >= 2 && k2 <= 12) { const float g = gw.g[k2-2];
                o2.x += g*v.x; o2.y += g*v.y; o2.z += g*v.z; o2.w += g*v.w; }
            if (k2 >= 3) { const float g = gw.g[k2-3];
                o3.x += g*v.x; o3.y += g*v.y; o3.z += g*v.z; o3.w += g*v.w; }
        }
        const int obase = hf * PLANE_I + slice + (h0 + hr0) * NX + w0 + hq4;
        *(float4*)(A + obase)          = o0;
        *(float4*)(A + obase + NX)     = o1;
        *(float4*)(A + obase + 2*NX)   = o2;
        *(float4*)(A + obase + 3*NX)   = o3;
    }
}

// k_d: D-blur with register sliding window + SSIM + block reduce.
// (proven config: DCHUNK=40, 800 blocks, no outer unroll)
__global__ __launch_bounds__(256) void k_d(const float* __restrict__ A,
                                           float* __restrict__ partial,
                                           GaussW gw) {
    const int tid = threadIdx.x;
    const long long gidx = (long long)blockIdx.x * 256 + tid;
    const int NCOL = NB * NX * NX;
    const int chunk = (int)(gidx / NCOL);
    const int col   = (int)(gidx % NCOL);
    const int b  = col / (NX * NX);
    const int hw = col % (NX * NX);
    const int base = b * (NX * NXY) + hw;
    const int d0 = chunk * DCHUNK;

    float win[5][WS];
    #pragma unroll
    for (int i = 0; i < WS; ++i) {
        const int di = d0 - 5 + i;
        const bool ok = (di >= 0 && di < NX);
        const int o = base + (ok ? di : 0) * NXY;
        #pragma unroll
        for (int f = 0; f < 5; ++f)
            win[f][i] = ok ? A[f * PLANE_I + o] : 0.f;
    }

    float acc = 0.f;
    for (int dd = 0; dd < DCHUNK; ++dd) {
        float m[5];
        #pragma unroll
        for (int f = 0; f < 5; ++f) {
            float s = 0.f;
            #pragma unroll
            for (int i = 0; i < WS; ++i) s += gw.g[i] * win[f][i];
            m[f] = s;
        }
        const float mux = m[0], muy = m[1];
        const float mux2 = mux * mux, muy2 = muy * muy, muxy = mux * muy;
        const float sxx = m[2] - mux2, syy = m[3] - muy2, sxy = m[4] - muxy;
        const float num = (2.f * muxy + 1.0e-4f) * (2.f * sxy + 9.0e-4f);
        const float den = (mux2 + muy2 + 1.0e-4f) * (sxx + syy + 9.0e-4f);
        acc += num / den;

        const int dn = d0 + dd + 6;
        const bool ok = (dn < NX);
        const int o = base + (ok ? dn : 0) * NXY;
        #pragma unroll
        for (int f = 0; f < 5; ++f) {
            #pragma unroll
            for (int i = 0; i < WS - 1; ++i) win[f][i] = win[f][i + 1];
            win[f][WS - 1] = ok ? A[f * PLANE_I + o] : 0.f;
        }
    }

    for (int off = 32; off > 0; off >>= 1) acc += __shfl_down(acc, off, 64);
    __shared__ float wsum[4];
    if ((tid & 63) == 0) wsum[tid >> 6] = acc;
    __syncthreads();
    if (tid == 0) partial[blockIdx.x] = wsum[0] + wsum[1] + wsum[2] + wsum[3];
}

__global__ __launch_bounds__(256) void k_red(const float* __restrict__ partial,
                                             int n, float* __restrict__ out) {
    double s = 0.0;
    for (int i = threadIdx.x; i < n; i += 256) s += (double)partial[i];
    __shared__ double sd[256];
    sd[threadIdx.x] = s;
    __syncthreads();
    for (int st = 128; st > 0; st >>= 1) {
        if (threadIdx.x < st) sd[threadIdx.x] += sd[threadIdx.x + st];
        __syncthreads();
    }
    if (threadIdx.x == 0)
        out[0] = (float)(sd[0] / (double)((long long)NB * NX * NXY));
}

extern "C" void kernel_launch(void* const* d_in, const int* in_sizes, int n_in,
                              void* d_out, int out_size, void* d_ws, size_t ws_size,
                              hipStream_t stream) {
    const float* x = (const float*)d_in[0];
    const float* y = (const float*)d_in[1];
    float* A = (float*)d_ws;
    float* partial = (float*)((char*)d_ws + (size_t)5 * PLANE_I * sizeof(float));

    GaussW gw;
    {
        float tmp[WS]; float s = 0.f;
        for (int i = 0; i < WS; ++i) {
            const double e = exp(-(double)((i - 5) * (i - 5)) / 4.5);
            tmp[i] = (float)e; s += tmp[i];
        }
        for (int i = 0; i < WS; ++i) gw.g[i] = tmp[i] / s;
    }

    dim3 g1(NX / TW, NX / TH, NB * NX);   // (5,10,320) = 16000 blocks
    k_wh<<<g1, 256, 0, stream>>>(x, y, A, gw);

    const int nblk2 = (NB * NX * NX * (NX / DCHUNK)) / 256;  // 800
    k_d<<<nblk2, 256, 0, stream>>>(A, partial, gw);

    k_red<<<1, 256, 0, stream>>>(partial, nblk2, (float*)d_out);
}